// Round 1
// baseline (703.042 us; speedup 1.0000x reference)
//
#include <hip/hip_runtime.h>
#include <math.h>

#define Vc 5
#define Cc 32
#define Gc 8
#define Dc 32
#define Hc 192
#define Wc 192
#define HWc (Hc*Wc)
#define NSRC (Vc-1)

// output offsets (floats)
#define OFF_DEPTH  0
#define OFF_CONF   (HWc)
#define OFF_ATTN   (2*HWc)
#define OFF_EST    (OFF_ATTN + Dc*HWc)
#define OFF_SW     (OFF_EST + 3*HWc)
#define OFF_WEIGHT (OFF_SW + HWc)
#define OFF_NVAL   (OFF_WEIGHT + NSRC*HWc)
#define OFF_MIN    (OFF_NVAL + Dc*HWc)
#define OFF_MAX    (OFF_MIN + HWc)

// ws layout (floats): [0]=hmin bits(uint) [1]=hmax bits(uint) [2 + i*15]: rot(9), trans(3), norv(3)

__device__ void inv4(const float* A, float* out) {
    float M[4][8];
    for (int r = 0; r < 4; r++) {
        for (int c = 0; c < 4; c++) { M[r][c] = A[r*4+c]; M[r][c+4] = (r == c) ? 1.f : 0.f; }
    }
    for (int col = 0; col < 4; col++) {
        int piv = col; float best = fabsf(M[col][col]);
        for (int r = col+1; r < 4; r++) { float v = fabsf(M[r][col]); if (v > best) { best = v; piv = r; } }
        if (piv != col) for (int c = 0; c < 8; c++) { float t = M[col][c]; M[col][c] = M[piv][c]; M[piv][c] = t; }
        float inv = 1.f / M[col][col];
        for (int c = 0; c < 8; c++) M[col][c] *= inv;
        for (int r = 0; r < 4; r++) {
            if (r == col) continue;
            float f = M[r][col];
            for (int c = 0; c < 8; c++) M[r][c] -= f * M[col][c];
        }
    }
    for (int r = 0; r < 4; r++) for (int c = 0; c < 4; c++) out[r*4+c] = M[r][c+4];
}

__device__ void inv3(const float* A, float* out) {
    float a=A[0],b=A[1],c=A[2],d=A[3],e=A[4],f=A[5],g=A[6],h=A[7],i=A[8];
    float det = a*(e*i-f*h) - b*(d*i-f*g) + c*(d*h-e*g);
    float id = 1.f/det;
    out[0]=(e*i-f*h)*id; out[1]=(c*h-b*i)*id; out[2]=(b*f-c*e)*id;
    out[3]=(f*g-d*i)*id; out[4]=(a*i-c*g)*id; out[5]=(c*d-a*f)*id;
    out[6]=(d*h-e*g)*id; out[7]=(b*g-a*h)*id; out[8]=(a*e-b*d)*id;
}

__global__ void setup_kernel(const float* __restrict__ rotation,
                             const float* __restrict__ proj,
                             float* __restrict__ wsf) {
    if (threadIdx.x != 0 || blockIdx.x != 0) return;
    unsigned int* wsu = (unsigned int*)wsf;
    wsu[0] = 0x7F800000u;  // +inf  (hmin)
    wsu[1] = 0u;           // 0.0   (hmax; depths positive)

    float refE[16], refK[16], refNew[16], invRef[16];
    for (int k = 0; k < 16; k++) { refE[k] = proj[k]; refK[k] = proj[16+k]; }
    for (int k = 0; k < 16; k++) refNew[k] = refE[k];
    for (int r = 0; r < 3; r++) for (int c = 0; c < 4; c++) {
        float s = 0.f;
        for (int k = 0; k < 3; k++) s += refK[r*4+k] * refE[k*4+c];
        refNew[r*4+c] = s;
    }
    inv4(refNew, invRef);
    float invR0[9];
    inv3(rotation, invR0);

    for (int i = 0; i < NSRC; i++) {
        const float* E = proj + (i+1)*32;
        const float* K = proj + (i+1)*32 + 16;
        float sNew[16];
        for (int k = 0; k < 16; k++) sNew[k] = E[k];
        for (int r = 0; r < 3; r++) for (int c = 0; c < 4; c++) {
            float s = 0.f;
            for (int k = 0; k < 3; k++) s += K[r*4+k] * E[k*4+c];
            sNew[r*4+c] = s;
        }
        float P[16];
        for (int r = 0; r < 4; r++) for (int c = 0; c < 4; c++) {
            float s = 0.f;
            for (int k = 0; k < 4; k++) s += sNew[r*4+k] * invRef[k*4+c];
            P[r*4+c] = s;
        }
        float* o = wsf + 2 + i*15;
        for (int r = 0; r < 3; r++) for (int c = 0; c < 3; c++) o[r*3+c] = P[r*4+c];
        for (int r = 0; r < 3; r++) o[9+r] = P[r*4+3];
        const float* Ri = rotation + (i+1)*9;
        for (int c = 0; c < 3; c++) {
            float s = 0.f;
            for (int k = 0; k < 3; k++) s += Ri[2*3+k] * invR0[k*3+c];
            o[12+c] = s;
        }
    }
}

__global__ void minmax_kernel(const float* __restrict__ depth, unsigned int* __restrict__ wsu) {
    int idx = blockIdx.x * blockDim.x + threadIdx.x;
    float v = (idx < Dc*HWc) ? depth[idx] : depth[0];
    float mn = v, mx = v;
    for (int off = 1; off < 64; off <<= 1) {
        mn = fminf(mn, __shfl_xor(mn, off));
        mx = fmaxf(mx, __shfl_xor(mx, off));
    }
    if ((threadIdx.x & 63) == 0) {
        atomicMin(&wsu[0], __float_as_uint(mn));
        atomicMax(&wsu[1], __float_as_uint(mx));
    }
}

__global__ __launch_bounds__(256)
void main_kernel(const float* __restrict__ ref_feature,
                 const float* __restrict__ src_features,
                 const float* __restrict__ normal_plane,
                 const float* __restrict__ depth_hypo,
                 const float* __restrict__ w_reg,
                 const float* __restrict__ w_norm,
                 const float* __restrict__ wsf,
                 float* __restrict__ out) {
    const int pix = blockIdx.x;
    const int t = threadIdx.x;
    const int d = t & 31;
    const int g = t >> 5;
    const float fxp = (float)(pix % Wc);
    const float fyp = (float)(pix / Wc);

    __shared__ float s_cf[Gc*Dc];
    __shared__ float s_valid[Dc];

    float refv[4];
#pragma unroll
    for (int j = 0; j < 4; j++) refv[j] = ref_feature[(g*4+j)*HWc + pix];
    const float np0 = normal_plane[0*HWc + pix];
    const float np1 = normal_plane[1*HWc + pix];
    const float np2 = normal_plane[2*HWc + pix];
    const float depth_d = depth_hypo[d*HWc + pix];
    const float wreg_g = w_reg[g];

    float acc_cor = 0.f;     // per (g,d)
    float cws_acc = 1e-8f;   // per d (redundant across g)
    float sumw_acc = 1e-8f;  // per d
    float nval_acc = 0.f;    // per d

    for (int i = 0; i < NSRC; i++) {
        const float* Wv = wsf + 2 + i*15;
        const float r00=Wv[0], r01=Wv[1], r02=Wv[2];
        const float r10=Wv[3], r11=Wv[4], r12=Wv[5];
        const float r20=Wv[6], r21=Wv[7], r22=Wv[8];
        const float t0=Wv[9], t1=Wv[10], t2=Wv[11];
        const float nv0=Wv[12], nv1=Wv[13], nv2=Wv[14];

        const float b0 = r00*fxp + r01*fyp + r02;
        const float b1 = r10*fxp + r11*fyp + r12;
        const float b2 = r20*fxp + r21*fyp + r22;

        float z = b2*depth_d + t2;
        if (z == 0.f) z = 1e-9f;
        const float px = (b0*depth_d + t0) / z;
        const float py = (b1*depth_d + t1) / z;

        const float fx0 = floorf(px), fy0 = floorf(py);
        const float wx = px - fx0, wy = py - fy0;
        const float fx1 = fx0 + 1.f, fy1 = fy0 + 1.f;
        const bool ix0 = (fx0 >= 0.f) && (fx0 <= (float)(Wc-1));
        const bool ix1 = (fx1 >= 0.f) && (fx1 <= (float)(Wc-1));
        const bool iy0 = (fy0 >= 0.f) && (fy0 <= (float)(Hc-1));
        const bool iy1 = (fy1 >= 0.f) && (fy1 <= (float)(Hc-1));
        const float w00 = (1.f-wx)*(1.f-wy) * ((ix0 && iy0) ? 1.f : 0.f);
        const float w10 = wx*(1.f-wy)       * ((ix1 && iy0) ? 1.f : 0.f);
        const float w01 = (1.f-wx)*wy       * ((ix0 && iy1) ? 1.f : 0.f);
        const float w11 = wx*wy             * ((ix1 && iy1) ? 1.f : 0.f);
        const int xi0 = (int)fminf(fmaxf(fx0, 0.f), (float)(Wc-1));
        const int xi1 = (int)fminf(fmaxf(fx1, 0.f), (float)(Wc-1));
        const int yi0 = (int)fminf(fmaxf(fy0, 0.f), (float)(Hc-1));
        const int yi1 = (int)fminf(fmaxf(fy1, 0.f), (float)(Hc-1));
        const int o00 = yi0*Wc + xi0, o10 = yi0*Wc + xi1;
        const int o01 = yi1*Wc + xi0, o11 = yi1*Wc + xi1;

        const float* src = src_features + (size_t)i * Cc * HWc;
        float corfeat = 0.f;
        float warp0 = 0.f;
#pragma unroll
        for (int j = 0; j < 4; j++) {
            const float* sc = src + (g*4 + j) * HWc;
            float v = w00*sc[o00] + w10*sc[o10] + w01*sc[o01] + w11*sc[o11];
            if (j == 0) warp0 = v;
            corfeat += v * refv[j];
        }
        corfeat *= 0.25f;

        s_cf[t] = corfeat;
        if (g == 0) s_valid[d] = (warp0 != 0.f) ? 1.f : 0.f;
        __syncthreads();

        float s_d = 0.f;
#pragma unroll
        for (int gg = 0; gg < Gc; gg++) s_d += s_cf[gg*32 + d];
        // softmax over d within 32-lane halves
        float m = s_d;
        for (int off = 1; off < 32; off <<= 1) m = fmaxf(m, __shfl_xor(m, off));
        float e = expf(s_d - m);
        float se = e;
        for (int off = 1; off < 32; off <<= 1) se += __shfl_xor(se, off);
        const float cor_w = (e / se) * 0.17677669529663687f; // softmax / sqrt(C)

        const float valid = s_valid[d];
        const float src_w = fmaxf(np0*nv0 + np1*nv1 + np2*nv2, 0.f) + 0.01f;
        const float sw = src_w * valid;

        acc_cor += cor_w * sw * corfeat;
        cws_acc += cor_w;
        sumw_acc += sw;
        nval_acc += valid;

        // sims: mean over d of sw
        float ssum = sw;
        for (int off = 1; off < 32; off <<= 1) ssum += __shfl_xor(ssum, off);
        if (t == 0) out[OFF_WEIGHT + i*HWc + pix] = ssum * (1.f/32.f);
        __syncthreads();
    }

    // finalize
    const float cf_final = acc_cor / sumw_acc / cws_acc;
    s_cf[t] = cf_final * wreg_g;
    __syncthreads();
    float logit = 0.f;
#pragma unroll
    for (int gg = 0; gg < Gc; gg++) logit += s_cf[gg*32 + d];

    const unsigned int* wsu = (const unsigned int*)wsf;
    const float hmin = __uint_as_float(wsu[0]);
    const float hmax = __uint_as_float(wsu[1]);
    logit += (depth_d - hmin) / (hmax - hmin);

    float m = logit;
    for (int off = 1; off < 32; off <<= 1) m = fmaxf(m, __shfl_xor(m, off));
    float e = expf(logit - m);
    float se = e;
    for (int off = 1; off < 32; off <<= 1) se += __shfl_xor(se, off);
    const float attn = e / se;

    // argmax over d on attn (first occurrence on ties)
    float av = attn; int ai = d;
    for (int off = 1; off < 32; off <<= 1) {
        float av2 = __shfl_xor(av, off);
        int ai2 = __shfl_xor(ai, off);
        if (av2 > av || (av2 == av && ai2 < ai)) { av = av2; ai = ai2; }
    }
    const float dep_sel = __shfl(depth_d, ai, 32);
    const float dep0 = __shfl(depth_d, 0, 32);
    const float dep1 = __shfl(depth_d, 1, 32);
    const float last_itv = dep1 - dep0;

    if (t < 32) {
        out[OFF_ATTN + d*HWc + pix] = attn;
        out[OFF_NVAL + d*HWc + pix] = nval_acc;
    }
    if (t == 0) {
        out[OFF_DEPTH + pix] = dep_sel;
        out[OFF_CONF + pix] = av;
        out[OFF_SW + pix] = sumw_acc * 0.25f;   // sum_weight[:,0,0] / nsrc, d==0 lane
        out[OFF_MIN + pix] = dep_sel - last_itv;
        out[OFF_MAX + pix] = dep_sel + last_itv;
    }
    if (t < 3) {
        float v = np0*w_norm[t*3+0] + np1*w_norm[t*3+1] + np2*w_norm[t*3+2];
        out[OFF_EST + t*HWc + pix] = v;
    }
}

extern "C" void kernel_launch(void* const* d_in, const int* in_sizes, int n_in,
                              void* d_out, int out_size, void* d_ws, size_t ws_size,
                              hipStream_t stream) {
    const float* ref   = (const float*)d_in[0];
    const float* src   = (const float*)d_in[1];
    const float* rot   = (const float*)d_in[2];
    const float* np_   = (const float*)d_in[3];
    const float* proj  = (const float*)d_in[4];
    const float* dh    = (const float*)d_in[5];
    const float* wreg  = (const float*)d_in[6];
    const float* wnorm = (const float*)d_in[7];
    float* out = (float*)d_out;
    float* ws  = (float*)d_ws;

    setup_kernel<<<1, 1, 0, stream>>>(rot, proj, ws);
    minmax_kernel<<<(Dc*HWc + 255)/256, 256, 0, stream>>>(dh, (unsigned int*)ws);
    main_kernel<<<HWc, 256, 0, stream>>>(ref, src, np_, dh, wreg, wnorm, ws, out);
}

// Round 2
// 285.784 us; speedup vs baseline: 2.4600x; 2.4600x over previous
//
#include <hip/hip_runtime.h>
#include <math.h>

#define Vc 5
#define Cc 32
#define Gc 8
#define Dc 32
#define Hc 192
#define Wc 192
#define HWc (Hc*Wc)
#define NSRC (Vc-1)

// output offsets (floats)
#define OFF_DEPTH  0
#define OFF_CONF   (HWc)
#define OFF_ATTN   (2*HWc)
#define OFF_EST    (OFF_ATTN + Dc*HWc)
#define OFF_SW     (OFF_EST + 3*HWc)
#define OFF_WEIGHT (OFF_SW + HWc)
#define OFF_NVAL   (OFF_WEIGHT + NSRC*HWc)
#define OFF_MIN    (OFF_NVAL + Dc*HWc)
#define OFF_MAX    (OFF_MIN + HWc)

// ws layout (floats): [0]=hmin bits(uint) [1]=hmax bits(uint) [2 + i*15]: rot(9), trans(3), norv(3)

__device__ void inv4(const float* A, float* out) {
    float M[4][8];
    for (int r = 0; r < 4; r++) {
        for (int c = 0; c < 4; c++) { M[r][c] = A[r*4+c]; M[r][c+4] = (r == c) ? 1.f : 0.f; }
    }
    for (int col = 0; col < 4; col++) {
        int piv = col; float best = fabsf(M[col][col]);
        for (int r = col+1; r < 4; r++) { float v = fabsf(M[r][col]); if (v > best) { best = v; piv = r; } }
        if (piv != col) for (int c = 0; c < 8; c++) { float t = M[col][c]; M[col][c] = M[piv][c]; M[piv][c] = t; }
        float inv = 1.f / M[col][col];
        for (int c = 0; c < 8; c++) M[col][c] *= inv;
        for (int r = 0; r < 4; r++) {
            if (r == col) continue;
            float f = M[r][col];
            for (int c = 0; c < 8; c++) M[r][c] -= f * M[col][c];
        }
    }
    for (int r = 0; r < 4; r++) for (int c = 0; c < 4; c++) out[r*4+c] = M[r][c+4];
}

__device__ void inv3(const float* A, float* out) {
    float a=A[0],b=A[1],c=A[2],d=A[3],e=A[4],f=A[5],g=A[6],h=A[7],i=A[8];
    float det = a*(e*i-f*h) - b*(d*i-f*g) + c*(d*h-e*g);
    float id = 1.f/det;
    out[0]=(e*i-f*h)*id; out[1]=(c*h-b*i)*id; out[2]=(b*f-c*e)*id;
    out[3]=(f*g-d*i)*id; out[4]=(a*i-c*g)*id; out[5]=(c*d-a*f)*id;
    out[6]=(d*h-e*g)*id; out[7]=(b*g-a*h)*id; out[8]=(a*e-b*d)*id;
}

__global__ void setup_kernel(const float* __restrict__ rotation,
                             const float* __restrict__ proj,
                             float* __restrict__ wsf) {
    if (threadIdx.x != 0 || blockIdx.x != 0) return;
    unsigned int* wsu = (unsigned int*)wsf;
    wsu[0] = 0x7F800000u;  // +inf  (hmin)
    wsu[1] = 0u;           // 0.0   (hmax; depths positive)

    float refE[16], refK[16], refNew[16], invRef[16];
    for (int k = 0; k < 16; k++) { refE[k] = proj[k]; refK[k] = proj[16+k]; }
    for (int k = 0; k < 16; k++) refNew[k] = refE[k];
    for (int r = 0; r < 3; r++) for (int c = 0; c < 4; c++) {
        float s = 0.f;
        for (int k = 0; k < 3; k++) s += refK[r*4+k] * refE[k*4+c];
        refNew[r*4+c] = s;
    }
    inv4(refNew, invRef);
    float invR0[9];
    inv3(rotation, invR0);

    for (int i = 0; i < NSRC; i++) {
        const float* E = proj + (i+1)*32;
        const float* K = proj + (i+1)*32 + 16;
        float sNew[16];
        for (int k = 0; k < 16; k++) sNew[k] = E[k];
        for (int r = 0; r < 3; r++) for (int c = 0; c < 4; c++) {
            float s = 0.f;
            for (int k = 0; k < 3; k++) s += K[r*4+k] * E[k*4+c];
            sNew[r*4+c] = s;
        }
        float P[16];
        for (int r = 0; r < 4; r++) for (int c = 0; c < 4; c++) {
            float s = 0.f;
            for (int k = 0; k < 4; k++) s += sNew[r*4+k] * invRef[k*4+c];
            P[r*4+c] = s;
        }
        float* o = wsf + 2 + i*15;
        for (int r = 0; r < 3; r++) for (int c = 0; c < 3; c++) o[r*3+c] = P[r*4+c];
        for (int r = 0; r < 3; r++) o[9+r] = P[r*4+3];
        const float* Ri = rotation + (i+1)*9;
        for (int c = 0; c < 3; c++) {
            float s = 0.f;
            for (int k = 0; k < 3; k++) s += Ri[2*3+k] * invR0[k*3+c];
            o[12+c] = s;
        }
    }
}

// Grid-stride min/max: 64 blocks x 256 threads, float4 loads, wave shuffle
// reduce -> LDS across 4 waves -> ONE atomicMin + ONE atomicMax per block.
// (R1: 4608 blocks x 4 waves x 2 atomics to the same 2 addresses = 420us of
//  cross-XCD atomic serialization. Guideline 12.)
__global__ __launch_bounds__(256)
void minmax_kernel(const float* __restrict__ depth, unsigned int* __restrict__ wsu) {
    const int tid = blockIdx.x * blockDim.x + threadIdx.x;
    const int stride = gridDim.x * blockDim.x;
    const int n4 = (Dc*HWc) / 4;   // 1179648 / 4 = 294912, divides evenly
    const float4* d4 = (const float4*)depth;
    float mn = __uint_as_float(0x7F800000u);  // +inf
    float mx = 0.f;                           // depths positive
    for (int idx = tid; idx < n4; idx += stride) {
        float4 v = d4[idx];
        mn = fminf(mn, fminf(fminf(v.x, v.y), fminf(v.z, v.w)));
        mx = fmaxf(mx, fmaxf(fmaxf(v.x, v.y), fmaxf(v.z, v.w)));
    }
    for (int off = 32; off; off >>= 1) {
        mn = fminf(mn, __shfl_xor(mn, off));
        mx = fmaxf(mx, __shfl_xor(mx, off));
    }
    __shared__ float smn[4], smx[4];
    const int w = threadIdx.x >> 6;
    if ((threadIdx.x & 63) == 0) { smn[w] = mn; smx[w] = mx; }
    __syncthreads();
    if (threadIdx.x == 0) {
        for (int i = 1; i < 4; i++) { mn = fminf(mn, smn[i]); mx = fmaxf(mx, smx[i]); }
        atomicMin(&wsu[0], __float_as_uint(mn));
        atomicMax(&wsu[1], __float_as_uint(mx));
    }
}

__global__ __launch_bounds__(256)
void main_kernel(const float* __restrict__ ref_feature,
                 const float* __restrict__ src_features,
                 const float* __restrict__ normal_plane,
                 const float* __restrict__ depth_hypo,
                 const float* __restrict__ w_reg,
                 const float* __restrict__ w_norm,
                 const float* __restrict__ wsf,
                 float* __restrict__ out) {
    const int pix = blockIdx.x;
    const int t = threadIdx.x;
    const int d = t & 31;
    const int g = t >> 5;
    const float fxp = (float)(pix % Wc);
    const float fyp = (float)(pix / Wc);

    __shared__ float s_cf[Gc*Dc];
    __shared__ float s_valid[Dc];

    float refv[4];
#pragma unroll
    for (int j = 0; j < 4; j++) refv[j] = ref_feature[(g*4+j)*HWc + pix];
    const float np0 = normal_plane[0*HWc + pix];
    const float np1 = normal_plane[1*HWc + pix];
    const float np2 = normal_plane[2*HWc + pix];
    const float depth_d = depth_hypo[d*HWc + pix];
    const float wreg_g = w_reg[g];

    float acc_cor = 0.f;     // per (g,d)
    float cws_acc = 1e-8f;   // per d (redundant across g)
    float sumw_acc = 1e-8f;  // per d
    float nval_acc = 0.f;    // per d

    for (int i = 0; i < NSRC; i++) {
        const float* Wv = wsf + 2 + i*15;
        const float r00=Wv[0], r01=Wv[1], r02=Wv[2];
        const float r10=Wv[3], r11=Wv[4], r12=Wv[5];
        const float r20=Wv[6], r21=Wv[7], r22=Wv[8];
        const float t0=Wv[9], t1=Wv[10], t2=Wv[11];
        const float nv0=Wv[12], nv1=Wv[13], nv2=Wv[14];

        const float b0 = r00*fxp + r01*fyp + r02;
        const float b1 = r10*fxp + r11*fyp + r12;
        const float b2 = r20*fxp + r21*fyp + r22;

        float z = b2*depth_d + t2;
        if (z == 0.f) z = 1e-9f;
        const float px = (b0*depth_d + t0) / z;
        const float py = (b1*depth_d + t1) / z;

        const float fx0 = floorf(px), fy0 = floorf(py);
        const float wx = px - fx0, wy = py - fy0;
        const float fx1 = fx0 + 1.f, fy1 = fy0 + 1.f;
        const bool ix0 = (fx0 >= 0.f) && (fx0 <= (float)(Wc-1));
        const bool ix1 = (fx1 >= 0.f) && (fx1 <= (float)(Wc-1));
        const bool iy0 = (fy0 >= 0.f) && (fy0 <= (float)(Hc-1));
        const bool iy1 = (fy1 >= 0.f) && (fy1 <= (float)(Hc-1));
        const float w00 = (1.f-wx)*(1.f-wy) * ((ix0 && iy0) ? 1.f : 0.f);
        const float w10 = wx*(1.f-wy)       * ((ix1 && iy0) ? 1.f : 0.f);
        const float w01 = (1.f-wx)*wy       * ((ix0 && iy1) ? 1.f : 0.f);
        const float w11 = wx*wy             * ((ix1 && iy1) ? 1.f : 0.f);
        const int xi0 = (int)fminf(fmaxf(fx0, 0.f), (float)(Wc-1));
        const int xi1 = (int)fminf(fmaxf(fx1, 0.f), (float)(Wc-1));
        const int yi0 = (int)fminf(fmaxf(fy0, 0.f), (float)(Hc-1));
        const int yi1 = (int)fminf(fmaxf(fy1, 0.f), (float)(Hc-1));
        const int o00 = yi0*Wc + xi0, o10 = yi0*Wc + xi1;
        const int o01 = yi1*Wc + xi0, o11 = yi1*Wc + xi1;

        const float* src = src_features + (size_t)i * Cc * HWc;
        float corfeat = 0.f;
        float warp0 = 0.f;
#pragma unroll
        for (int j = 0; j < 4; j++) {
            const float* sc = src + (g*4 + j) * HWc;
            float v = w00*sc[o00] + w10*sc[o10] + w01*sc[o01] + w11*sc[o11];
            if (j == 0) warp0 = v;
            corfeat += v * refv[j];
        }
        corfeat *= 0.25f;

        s_cf[t] = corfeat;
        if (g == 0) s_valid[d] = (warp0 != 0.f) ? 1.f : 0.f;
        __syncthreads();

        float s_d = 0.f;
#pragma unroll
        for (int gg = 0; gg < Gc; gg++) s_d += s_cf[gg*32 + d];
        // softmax over d within 32-lane halves
        float m = s_d;
        for (int off = 1; off < 32; off <<= 1) m = fmaxf(m, __shfl_xor(m, off));
        float e = expf(s_d - m);
        float se = e;
        for (int off = 1; off < 32; off <<= 1) se += __shfl_xor(se, off);
        const float cor_w = (e / se) * 0.17677669529663687f; // softmax / sqrt(C)

        const float valid = s_valid[d];
        const float src_w = fmaxf(np0*nv0 + np1*nv1 + np2*nv2, 0.f) + 0.01f;
        const float sw = src_w * valid;

        acc_cor += cor_w * sw * corfeat;
        cws_acc += cor_w;
        sumw_acc += sw;
        nval_acc += valid;

        // sims: mean over d of sw
        float ssum = sw;
        for (int off = 1; off < 32; off <<= 1) ssum += __shfl_xor(ssum, off);
        if (t == 0) out[OFF_WEIGHT + i*HWc + pix] = ssum * (1.f/32.f);
        __syncthreads();
    }

    // finalize
    const float cf_final = acc_cor / sumw_acc / cws_acc;
    s_cf[t] = cf_final * wreg_g;
    __syncthreads();
    float logit = 0.f;
#pragma unroll
    for (int gg = 0; gg < Gc; gg++) logit += s_cf[gg*32 + d];

    const unsigned int* wsu = (const unsigned int*)wsf;
    const float hmin = __uint_as_float(wsu[0]);
    const float hmax = __uint_as_float(wsu[1]);
    logit += (depth_d - hmin) / (hmax - hmin);

    float m = logit;
    for (int off = 1; off < 32; off <<= 1) m = fmaxf(m, __shfl_xor(m, off));
    float e = expf(logit - m);
    float se = e;
    for (int off = 1; off < 32; off <<= 1) se += __shfl_xor(se, off);
    const float attn = e / se;

    // argmax over d on attn (first occurrence on ties)
    float av = attn; int ai = d;
    for (int off = 1; off < 32; off <<= 1) {
        float av2 = __shfl_xor(av, off);
        int ai2 = __shfl_xor(ai, off);
        if (av2 > av || (av2 == av && ai2 < ai)) { av = av2; ai = ai2; }
    }
    const float dep_sel = __shfl(depth_d, ai, 32);
    const float dep0 = __shfl(depth_d, 0, 32);
    const float dep1 = __shfl(depth_d, 1, 32);
    const float last_itv = dep1 - dep0;

    if (t < 32) {
        out[OFF_ATTN + d*HWc + pix] = attn;
        out[OFF_NVAL + d*HWc + pix] = nval_acc;
    }
    if (t == 0) {
        out[OFF_DEPTH + pix] = dep_sel;
        out[OFF_CONF + pix] = av;
        out[OFF_SW + pix] = sumw_acc * 0.25f;   // sum_weight[:,0,0] / nsrc, d==0 lane
        out[OFF_MIN + pix] = dep_sel - last_itv;
        out[OFF_MAX + pix] = dep_sel + last_itv;
    }
    if (t < 3) {
        float v = np0*w_norm[t*3+0] + np1*w_norm[t*3+1] + np2*w_norm[t*3+2];
        out[OFF_EST + t*HWc + pix] = v;
    }
}

extern "C" void kernel_launch(void* const* d_in, const int* in_sizes, int n_in,
                              void* d_out, int out_size, void* d_ws, size_t ws_size,
                              hipStream_t stream) {
    const float* ref   = (const float*)d_in[0];
    const float* src   = (const float*)d_in[1];
    const float* rot   = (const float*)d_in[2];
    const float* np_   = (const float*)d_in[3];
    const float* proj  = (const float*)d_in[4];
    const float* dh    = (const float*)d_in[5];
    const float* wreg  = (const float*)d_in[6];
    const float* wnorm = (const float*)d_in[7];
    float* out = (float*)d_out;
    float* ws  = (float*)d_ws;

    setup_kernel<<<1, 1, 0, stream>>>(rot, proj, ws);
    minmax_kernel<<<64, 256, 0, stream>>>(dh, (unsigned int*)ws);
    main_kernel<<<HWc, 256, 0, stream>>>(ref, src, np_, dh, wreg, wnorm, ws, out);
}